// Round 7
// baseline (399.302 us; speedup 1.0000x reference)
//
#include <hip/hip_runtime.h>
#include <hip/hip_cooperative_groups.h>
namespace cg = cooperative_groups;

// MLP depends only on X[b] (1000 distinct values) -> params table, gathered
// by the scan. R6 landed the exact two-pass checkpoint scan with LDS-staged
// coalesced stores. R7: dispatch-count attack — aux chain fused into ONE
// cooperative kernel (grid.sync between stages), scan_a+scan_b fused into
// ONE kernel (checkpoints/masks via LDS, never global).

typedef unsigned int uint;
typedef unsigned char uchar;
typedef unsigned short ushort_t;
typedef __attribute__((ext_vector_type(8))) short short8;
typedef __attribute__((ext_vector_type(4))) float f32x4;
typedef __attribute__((ext_vector_type(4))) uint uint4v;

#define SS 1000
#define HH 512
#define TT 200
#define BB_ 65536
#define PP 5

#define OFF_EMB   0
#define OFF_B1    512000
#define OFF_B2    512512
#define OFF_WOUT  513024
#define OFF_BOUT  515584
#define CONV_TOT  515589

__device__ __forceinline__ float b2f(ushort_t u) {
    return __uint_as_float(((uint)u) << 16);
}
__device__ __forceinline__ ushort_t f2b(float f) {
    uint u = __float_as_uint(f);
    uint r = u + 0x7FFFu + ((u >> 16) & 1u);   // RNE
    return (ushort_t)(r >> 16);
}
// Per-wave dtype detect (R2-R6: dataset is f32; keep both paths).
__device__ __forceinline__ int detect_bf16(const uint* __restrict__ embed_raw,
                                           int tid) {
    uint w = embed_raw[tid & 63];
    uint e = (w >> 7) & 0xFFu;
    bool pl = (e >= 117u && e <= 130u);
    return __popcll(__ballot(pl)) >= 32 ? 1 : 0;
}
__device__ __forceinline__ ushort_t ld_bf16(const void* src, int idx, int fb) {
    return fb ? ((const ushort_t*)src)[idx] : f2b(((const float*)src)[idx]);
}

// The one true step. Identical fp ops/order in phase A and phase B so
// checkpoint-resumed trajectories are bit-exact.
__device__ __forceinline__ float bkt_step(float latent, bool yt,
                                          float oms, float omg, float A1,
                                          float A0, float g, float s,
                                          float oml, float l,
                                          float* correct_out) {
    float num1    = latent * oms;
    float correct = fmaf(latent, A1, g);
    float lats    = latent * s;
    float num = yt ? num1 : lats;
    float den = yt ? correct : fmaf(latent, A0, omg);
    float kt  = num * __builtin_amdgcn_rcpf(den);
    *correct_out = correct;
    float nxt = fmaf(kt, oml, l);
    return fminf(fmaxf(nxt, 1e-6f), 1.f - 1e-6f);
}

// One 16x16 MFMA output tile per wave; id in [0,2048): 64 m-tiles x 32 n-tiles.
__device__ __forceinline__ void mlp_tile(
    const ushort_t* __restrict__ A, const ushort_t* __restrict__ WT,
    const ushort_t* __restrict__ bias, ushort_t* __restrict__ H,
    int Mclamp, int id, int lane)
{
    int m_base = (id & 63) * 16;
    int n_base = (id >> 6) * 16;
    int lrow = lane & 15;
    int q = lane >> 4;
    int rowA = m_base + lrow; if (rowA > Mclamp) rowA = Mclamp;

    const short8* Ap = (const short8*)(A + (size_t)rowA * HH) + q;
    const short8* Bp = (const short8*)(WT + (size_t)(n_base + lrow) * HH) + q;

    f32x4 acc = {0.f, 0.f, 0.f, 0.f};
    #pragma unroll 8
    for (int kk = 0; kk < 16; kk++) {
        short8 a = Ap[kk * 4];
        short8 b = Bp[kk * 4];
        acc = __builtin_amdgcn_mfma_f32_16x16x32_bf16(a, b, acc, 0, 0, 0);
    }
    int orow = m_base + q * 4;                 // C/D: col=lane&15, row=q*4+reg
    int n = n_base + lrow;
    float bb = b2f(bias[n]);
    #pragma unroll
    for (int r = 0; r < 4; r++) {
        float v = acc[r] + bb;
        H[(size_t)(orow + r) * HH + n] = f2b(fmaxf(v, 0.f));
    }
}

// ---------------------------------------------------- aux (cooperative)
// 512 blocks x 256 (2 blocks/CU co-resident). Stages separated by
// grid.sync(): conv+transpose -> mlp1 -> mlp2 -> params.
__global__ __launch_bounds__(256, 2) void aux_kernel(
    const void* embed, const void* W1, const void* b1, const void* W2,
    const void* b2, const void* Wout, const void* bout,
    ushort_t* conv, ushort_t* WT1, ushort_t* WT2,
    ushort_t* h1, ushort_t* h2, float* table)
{
    cg::grid_group grid = cg::this_grid();
    __shared__ ushort_t t[32][33];
    int tid = threadIdx.x;
    int bx = blockIdx.x;
    int lane = tid & 63;
    int wave = tid >> 6;
    int fb = detect_bf16((const uint*)embed, tid);

    // stage 1a: conv copy (bf16-canonicalize all float inputs)
    for (int i = bx * 256 + tid; i < CONV_TOT; i += 512 * 256) {
        const void* src; int off;
        if      (i < OFF_B1)   { src = embed; off = i; }
        else if (i < OFF_B2)   { src = b1;    off = i - OFF_B1; }
        else if (i < OFF_WOUT) { src = b2;    off = i - OFF_B2; }
        else if (i < OFF_BOUT) { src = Wout;  off = i - OFF_WOUT; }
        else                   { src = bout;  off = i - OFF_BOUT; }
        conv[i] = ld_bf16(src, off, fb);
    }
    // stage 1b: one 32x32 transpose tile per block (512 tiles = W1+W2)
    {
        const void* W = bx < 256 ? W1 : W2;
        ushort_t* WT = bx < 256 ? WT1 : WT2;
        int ti = bx & 255;
        int k0 = (ti & 15) * 32, n0 = (ti >> 4) * 32;
        int tx = tid & 31, ty = tid >> 5;
        #pragma unroll
        for (int i = ty; i < 32; i += 8)
            t[i][tx] = ld_bf16(W, (k0 + i) * HH + n0 + tx, fb);
        __syncthreads();
        #pragma unroll
        for (int i = ty; i < 32; i += 8)
            WT[(n0 + i) * HH + k0 + tx] = t[tx][i];
    }
    grid.sync();

    int id = bx * 4 + wave;                    // 2048 wave-tiles, exact cover
    mlp_tile(conv + OFF_EMB, WT1, conv + OFF_B1, h1, SS - 1, id, lane);
    grid.sync();
    mlp_tile(h1, WT2, conv + OFF_B2, h2, 1023, id, lane);
    grid.sync();

    // stage 4: params (5000 wave-jobs over 2048 waves, 3 sweeps)
    const ushort_t* WoutC = conv + OFF_WOUT;
    const ushort_t* boutC = conv + OFF_BOUT;
    for (int wid = id; wid < SS * PP; wid += 2048) {
        int row = wid / PP, p = wid - row * PP;
        const short8* hr = (const short8*)(h2 + (size_t)row * HH);
        short8 h = hr[lane];
        float acc = 0.f;
        #pragma unroll
        for (int j = 0; j < 8; j++) {
            int k = lane * 8 + j;
            acc += b2f((ushort_t)h[j]) * b2f(WoutC[k * PP + p]);
        }
        #pragma unroll
        for (int m = 32; m; m >>= 1) acc += __shfl_xor(acc, m);
        if (lane == 0) {
            float x = acc + b2f(boutC[p]);
            float sg = 1.f / (1.f + expf(-x));
            sg = fminf(fmaxf(sg, 1e-6f), 1.f - 1e-6f);
            table[(size_t)row * 8 + p] = sg;
        }
    }
}

// ---------------------------------------------------------------- scan
// One block = 32 rows. Phase 0: y staged coalesced -> LDS nibbles.
// Phase A: 32 threads run the exact 200-step chain from LDS bits, drop 8
// checkpoints+masks to LDS. Phase B: 256 threads re-emit bit-identically
// into a 32x200 LDS tile; contiguous nontemporal uint4 stores.
__global__ __launch_bounds__(256) void scan_kernel(
    const int* __restrict__ X, const int* __restrict__ y,
    const float* __restrict__ table, const uint* __restrict__ embed_raw,
    void* __restrict__ out)
{
    __shared__ __align__(16) float stg[32 * 200];      // 25600 B
    __shared__ uchar ybit[32 * 50];                    // 1600 B
    __shared__ float cpL[8 * 32];                      // 1024 B
    __shared__ uint  maskL[8 * 32];                    // 1024 B
    int tid = threadIdx.x;
    int rbase = blockIdx.x * 32;
    int fb = detect_bf16(embed_raw, tid);

    // phase 0
    for (int idx = tid; idx < 1600; idx += 256) {
        int r = idx / 50, k = idx - r * 50;
        int4 v = *(const int4*)(y + (size_t)(rbase + r) * TT + k * 4);
        uint nib = (uint)(v.x == 1) | ((uint)(v.y == 1) << 1) |
                   ((uint)(v.z == 1) << 2) | ((uint)(v.w == 1) << 3);
        ybit[r * 50 + k] = (uchar)nib;
    }
    __syncthreads();

    // phase A: exact sequential chain, 1 thread/row
    if (tid < 32) {
        int rg = rbase + tid;
        int xi = X[rg]; xi = xi < 0 ? 0 : (xi >= SS ? SS - 1 : xi);
        float l      = table[xi * 8 + 0];
        float g      = table[xi * 8 + 2];
        float s      = table[xi * 8 + 3];
        float latent = table[xi * 8 + 4];
        float oms = 1.f - s, omg = 1.f - g, oml = 1.f - l;
        float A1 = 1.f - s - g, A0 = s + g - 1.f;
        int base = tid * 50;
        #pragma unroll
        for (int w = 0; w < 8; w++) {
            cpL[w * 32 + tid] = latent;
            uint m = 0;
            #pragma unroll
            for (int i = 0; i < 25; i++) {
                int t_ = w * 25 + i;
                uint bit = (ybit[base + (t_ >> 2)] >> (t_ & 3)) & 1u;
                m |= bit << i;
                float cd;
                latent = bkt_step(latent, bit, oms, omg, A1, A0, g, s, oml, l, &cd);
            }
            maskL[w * 32 + tid] = m;
        }
    }
    __syncthreads();

    // phase B: 8 threads/row re-emit
    int r = tid >> 3, j = tid & 7;
    int rg = rbase + r;
    int xi = X[rg]; xi = xi < 0 ? 0 : (xi >= SS ? SS - 1 : xi);
    float l  = table[xi * 8 + 0];
    float p1 = table[xi * 8 + 1];
    float g  = table[xi * 8 + 2];
    float s  = table[xi * 8 + 3];
    float L0 = table[xi * 8 + 4];

    if (j < 5) {
        float pv = j == 0 ? l : j == 1 ? p1 : j == 2 ? g : j == 3 ? s : L0;
        size_t po = 2ull * BB_ * TT + (size_t)rg * 5 + j;
        if (fb) ((ushort_t*)out)[po] = f2b(pv);
        else    ((float*)out)[po] = pv;
    }

    float latent = cpL[j * 32 + r];
    uint  u      = maskL[j * 32 + r];
    float oms = 1.f - s, omg = 1.f - g, oml = 1.f - l;
    float A1 = 1.f - s - g, A0 = s + g - 1.f;

    if (fb) {
        // bf16 path (unused on this dataset): direct scalar stores.
        ushort_t* cgb = (ushort_t*)out;
        ushort_t* lgb = (ushort_t*)out + (size_t)BB_ * TT;
        size_t eoff = (size_t)rg * TT + j * 25;
        #pragma unroll
        for (int i = 0; i < 25; i++) {
            float correct;
            float nxt = bkt_step(latent, (u >> i) & 1u,
                                 oms, omg, A1, A0, g, s, oml, l, &correct);
            cgb[eoff + i] = f2b(correct);
            lgb[eoff + i] = f2b(latent);
            latent = nxt;
        }
        return;                                // grid-uniform branch
    }

    float lat_arr[25];
    int sbase = r * 200 + j * 25;              // bank: (8r+25j)%32, 2-way = free
    #pragma unroll
    for (int i = 0; i < 25; i++) {
        float correct;
        float nxt = bkt_step(latent, (u >> i) & 1u,
                             oms, omg, A1, A0, g, s, oml, l, &correct);
        stg[sbase + i] = correct;
        lat_arr[i] = latent;
        latent = nxt;
    }
    __syncthreads();
    {
        const uint4v* src = (const uint4v*)stg;
        uint4v* dst = (uint4v*)((float*)out + (size_t)rbase * TT);
        for (int idx = tid; idx < 1600; idx += 256)
            __builtin_nontemporal_store(src[idx], dst + idx);
    }
    __syncthreads();
    #pragma unroll
    for (int i = 0; i < 25; i++)
        stg[sbase + i] = lat_arr[i];
    __syncthreads();
    {
        const uint4v* src = (const uint4v*)stg;
        uint4v* dst = (uint4v*)((float*)out + (size_t)BB_ * TT + (size_t)rbase * TT);
        for (int idx = tid; idx < 1600; idx += 256)
            __builtin_nontemporal_store(src[idx], dst + idx);
    }
}

// ---------------------------------------------------------------- launch
extern "C" void kernel_launch(void* const* d_in, const int* in_sizes, int n_in,
                              void* d_out, int out_size, void* d_ws, size_t ws_size,
                              hipStream_t stream) {
    const int* X = (const int*)d_in[0];
    const int* y = (const int*)d_in[1];

    char* ws = (char*)d_ws;
    ushort_t* conv  = (ushort_t*)(ws);
    ushort_t* WT1   = (ushort_t*)(ws + 1048576);
    ushort_t* WT2   = (ushort_t*)(ws + 1572864);
    ushort_t* h1    = (ushort_t*)(ws + 2097152);
    ushort_t* h2    = (ushort_t*)(ws + 3145728);
    float*    table = (float*)(ws + 4194304);

    const void* embed = d_in[2];
    const void* W1v   = d_in[3];
    const void* b1v   = d_in[4];
    const void* W2v   = d_in[5];
    const void* b2v   = d_in[6];
    const void* Woutv = d_in[7];
    const void* boutv = d_in[8];

    void* args[] = { &embed, &W1v, &b1v, &W2v, &b2v, &Woutv, &boutv,
                     &conv, &WT1, &WT2, &h1, &h2, &table };
    hipLaunchCooperativeKernel((const void*)aux_kernel, dim3(512), dim3(256),
                               args, 0u, stream);
    scan_kernel<<<dim3(2048, 1, 1), 256, 0, stream>>>(
        X, y, table, (const uint*)d_in[2], (void*)d_out);
}

// Round 8
// 387.916 us; speedup vs baseline: 1.0293x; 1.0293x over previous
//
#include <hip/hip_runtime.h>

// MLP depends only on X[b] (1000 distinct values) -> params table, gathered
// by the scan. R7 lesson: cooperative grid.sync costs ~60us each on gfx950
// (aux 200us, VALUBusy 0.9%) -> NO grid-wide sync. Instead each block carries
// 4 embedding rows through the whole MLP privately (LDS-local dataflow),
// reading W1/W2/Wout straight from global (L2-resident, reused 250x).
// Full-f32 math (no bf16 canonicalization) -> better absmax too.
// Scan = R6/R7's exact fused two-pass checkpoint scheme (unchanged).

typedef unsigned int uint;
typedef unsigned char uchar;
typedef unsigned short ushort_t;
typedef __attribute__((ext_vector_type(4))) uint uint4v;

#define SS 1000
#define HH 512
#define TT 200
#define BB_ 65536
#define PP 5

__device__ __forceinline__ float b2f(ushort_t u) {
    return __uint_as_float(((uint)u) << 16);
}
__device__ __forceinline__ ushort_t f2b(float f) {
    uint u = __float_as_uint(f);
    uint r = u + 0x7FFFu + ((u >> 16) & 1u);   // RNE
    return (ushort_t)(r >> 16);
}
// Per-wave dtype detect (R2-R7: dataset is f32; keep both paths).
__device__ __forceinline__ int detect_bf16(const uint* __restrict__ embed_raw,
                                           int tid) {
    uint w = embed_raw[tid & 63];
    uint e = (w >> 7) & 0xFFu;
    bool pl = (e >= 117u && e <= 130u);
    return __popcll(__ballot(pl)) >= 32 ? 1 : 0;
}
// load input element as f32 regardless of stored dtype
__device__ __forceinline__ float ldf(const void* src, size_t idx, int fb) {
    return fb ? b2f(((const ushort_t*)src)[idx]) : ((const float*)src)[idx];
}

// The one true scan step. Identical fp ops/order in phase A and phase B so
// checkpoint-resumed trajectories are bit-exact.
__device__ __forceinline__ float bkt_step(float latent, bool yt,
                                          float oms, float omg, float A1,
                                          float A0, float g, float s,
                                          float oml, float l,
                                          float* correct_out) {
    float num1    = latent * oms;
    float correct = fmaf(latent, A1, g);
    float lats    = latent * s;
    float num = yt ? num1 : lats;
    float den = yt ? correct : fmaf(latent, A0, omg);
    float kt  = num * __builtin_amdgcn_rcpf(den);
    *correct_out = correct;
    float nxt = fmaf(kt, oml, l);
    return fminf(fmaxf(nxt, 1e-6f), 1.f - 1e-6f);
}

// One dense layer for a 4-row tile: out[r][n] = relu(sum_k in[r][k]*W[k][n]+b[n]).
// Thread owns n and n+256. float4 LDS reads of `in`, 8 FMAs per W element.
__device__ __forceinline__ void layer4(const float* __restrict__ in,
                                       const void* __restrict__ W,
                                       const void* __restrict__ bias,
                                       float* __restrict__ outL,
                                       int fb, int tid) {
    int n0 = tid, n1 = tid + 256;
    float a00=0.f,a01=0.f,a02=0.f,a03=0.f;
    float a10=0.f,a11=0.f,a12=0.f,a13=0.f;
    for (int k = 0; k < HH; k += 4) {
        float4 e0 = *(const float4*)&in[0*HH + k];
        float4 e1 = *(const float4*)&in[1*HH + k];
        float4 e2 = *(const float4*)&in[2*HH + k];
        float4 e3 = *(const float4*)&in[3*HH + k];
        #pragma unroll
        for (int j = 0; j < 4; j++) {
            float w0 = ldf(W, (size_t)(k + j) * HH + n0, fb);
            float w1 = ldf(W, (size_t)(k + j) * HH + n1, fb);
            float ev0 = j==0?e0.x:j==1?e0.y:j==2?e0.z:e0.w;
            float ev1 = j==0?e1.x:j==1?e1.y:j==2?e1.z:e1.w;
            float ev2 = j==0?e2.x:j==1?e2.y:j==2?e2.z:e2.w;
            float ev3 = j==0?e3.x:j==1?e3.y:j==2?e3.z:e3.w;
            a00 = fmaf(ev0, w0, a00); a01 = fmaf(ev1, w0, a01);
            a02 = fmaf(ev2, w0, a02); a03 = fmaf(ev3, w0, a03);
            a10 = fmaf(ev0, w1, a10); a11 = fmaf(ev1, w1, a11);
            a12 = fmaf(ev2, w1, a12); a13 = fmaf(ev3, w1, a13);
        }
    }
    float bb0 = ldf(bias, n0, fb), bb1 = ldf(bias, n1, fb);
    outL[0*HH + n0] = fmaxf(a00 + bb0, 0.f);
    outL[1*HH + n0] = fmaxf(a01 + bb0, 0.f);
    outL[2*HH + n0] = fmaxf(a02 + bb0, 0.f);
    outL[3*HH + n0] = fmaxf(a03 + bb0, 0.f);
    outL[0*HH + n1] = fmaxf(a10 + bb1, 0.f);
    outL[1*HH + n1] = fmaxf(a11 + bb1, 0.f);
    outL[2*HH + n1] = fmaxf(a12 + bb1, 0.f);
    outL[3*HH + n1] = fmaxf(a13 + bb1, 0.f);
}

// ------------------------------------------------------------------- aux
// 250 blocks x 256: block b owns embed rows 4b..4b+3 through the whole MLP.
// No grid sync anywhere; W matrices read from global (L2-hot).
__global__ __launch_bounds__(256) void aux_kernel(
    const void* __restrict__ embed, const void* __restrict__ W1,
    const void* __restrict__ b1,    const void* __restrict__ W2,
    const void* __restrict__ b2,    const void* __restrict__ Wout,
    const void* __restrict__ bout,  float* __restrict__ table)
{
    __shared__ float eL[4 * HH];    // 8 KB
    __shared__ float hA[4 * HH];    // 8 KB
    __shared__ float hB[4 * HH];    // 8 KB
    int tid = threadIdx.x;
    int fb = detect_bf16((const uint*)embed, tid);
    int r0 = blockIdx.x * 4;

    for (int idx = tid; idx < 4 * HH; idx += 256) {
        int r = idx >> 9, k = idx & (HH - 1);
        eL[idx] = ldf(embed, (size_t)(r0 + r) * HH + k, fb);
    }
    __syncthreads();
    layer4(eL, W1, b1, hA, fb, tid);
    __syncthreads();
    layer4(hA, W2, b2, hB, fb, tid);
    __syncthreads();

    // params: 20 jobs (4 rows x 5 p), 8 threads/job (aligned within waves)
    if (tid < 160) {
        int job = tid >> 3, sub = tid & 7;
        int r = job / PP, p = job - r * PP;
        float acc = 0.f;
        for (int k = sub; k < HH; k += 8)
            acc += hB[r * HH + k] * ldf(Wout, (size_t)k * PP + p, fb);
        acc += __shfl_xor(acc, 1);
        acc += __shfl_xor(acc, 2);
        acc += __shfl_xor(acc, 4);
        if (sub == 0) {
            float x = acc + ldf(bout, p, fb);
            float sg = 1.f / (1.f + expf(-x));
            sg = fminf(fmaxf(sg, 1e-6f), 1.f - 1e-6f);
            table[(size_t)(r0 + r) * 8 + p] = sg;
        }
    }
}

// ---------------------------------------------------------------- scan
// One block = 32 rows. Phase 0: y staged coalesced -> LDS nibbles.
// Phase A: 32 threads run the exact 200-step chain, drop 8 checkpoints+masks
// to LDS. Phase B: 256 threads re-emit bit-identically into a 32x200 LDS
// tile; contiguous nontemporal uint4 stores (R5 lesson: per-lane strided
// stores caused 4.85x HBM write amplification).
__global__ __launch_bounds__(256) void scan_kernel(
    const int* __restrict__ X, const int* __restrict__ y,
    const float* __restrict__ table, const uint* __restrict__ embed_raw,
    void* __restrict__ out)
{
    __shared__ __align__(16) float stg[32 * 200];      // 25600 B
    __shared__ uchar ybit[32 * 50];                    // 1600 B
    __shared__ float cpL[8 * 32];
    __shared__ uint  maskL[8 * 32];
    int tid = threadIdx.x;
    int rbase = blockIdx.x * 32;
    int fb = detect_bf16(embed_raw, tid);

    for (int idx = tid; idx < 1600; idx += 256) {
        int r = idx / 50, k = idx - r * 50;
        int4 v = *(const int4*)(y + (size_t)(rbase + r) * TT + k * 4);
        uint nib = (uint)(v.x == 1) | ((uint)(v.y == 1) << 1) |
                   ((uint)(v.z == 1) << 2) | ((uint)(v.w == 1) << 3);
        ybit[r * 50 + k] = (uchar)nib;
    }
    __syncthreads();

    if (tid < 32) {
        int rg = rbase + tid;
        int xi = X[rg]; xi = xi < 0 ? 0 : (xi >= SS ? SS - 1 : xi);
        float l      = table[xi * 8 + 0];
        float g      = table[xi * 8 + 2];
        float s      = table[xi * 8 + 3];
        float latent = table[xi * 8 + 4];
        float oms = 1.f - s, omg = 1.f - g, oml = 1.f - l;
        float A1 = 1.f - s - g, A0 = s + g - 1.f;
        int base = tid * 50;
        #pragma unroll
        for (int w = 0; w < 8; w++) {
            cpL[w * 32 + tid] = latent;
            uint m = 0;
            #pragma unroll
            for (int i = 0; i < 25; i++) {
                int t_ = w * 25 + i;
                uint bit = (ybit[base + (t_ >> 2)] >> (t_ & 3)) & 1u;
                m |= bit << i;
                float cd;
                latent = bkt_step(latent, bit, oms, omg, A1, A0, g, s, oml, l, &cd);
            }
            maskL[w * 32 + tid] = m;
        }
    }
    __syncthreads();

    int r = tid >> 3, j = tid & 7;
    int rg = rbase + r;
    int xi = X[rg]; xi = xi < 0 ? 0 : (xi >= SS ? SS - 1 : xi);
    float l  = table[xi * 8 + 0];
    float p1 = table[xi * 8 + 1];
    float g  = table[xi * 8 + 2];
    float s  = table[xi * 8 + 3];
    float L0 = table[xi * 8 + 4];

    if (j < 5) {
        float pv = j == 0 ? l : j == 1 ? p1 : j == 2 ? g : j == 3 ? s : L0;
        size_t po = 2ull * BB_ * TT + (size_t)rg * 5 + j;
        if (fb) ((ushort_t*)out)[po] = f2b(pv);
        else    ((float*)out)[po] = pv;
    }

    float latent = cpL[j * 32 + r];
    uint  u      = maskL[j * 32 + r];
    float oms = 1.f - s, omg = 1.f - g, oml = 1.f - l;
    float A1 = 1.f - s - g, A0 = s + g - 1.f;

    if (fb) {
        ushort_t* cgb = (ushort_t*)out;
        ushort_t* lgb = (ushort_t*)out + (size_t)BB_ * TT;
        size_t eoff = (size_t)rg * TT + j * 25;
        #pragma unroll
        for (int i = 0; i < 25; i++) {
            float correct;
            float nxt = bkt_step(latent, (u >> i) & 1u,
                                 oms, omg, A1, A0, g, s, oml, l, &correct);
            cgb[eoff + i] = f2b(correct);
            lgb[eoff + i] = f2b(latent);
            latent = nxt;
        }
        return;                                // grid-uniform branch
    }

    float lat_arr[25];
    int sbase = r * 200 + j * 25;              // 2-way bank alias = free
    #pragma unroll
    for (int i = 0; i < 25; i++) {
        float correct;
        float nxt = bkt_step(latent, (u >> i) & 1u,
                             oms, omg, A1, A0, g, s, oml, l, &correct);
        stg[sbase + i] = correct;
        lat_arr[i] = latent;
        latent = nxt;
    }
    __syncthreads();
    {
        const uint4v* src = (const uint4v*)stg;
        uint4v* dst = (uint4v*)((float*)out + (size_t)rbase * TT);
        for (int idx = tid; idx < 1600; idx += 256)
            __builtin_nontemporal_store(src[idx], dst + idx);
    }
    __syncthreads();
    #pragma unroll
    for (int i = 0; i < 25; i++)
        stg[sbase + i] = lat_arr[i];
    __syncthreads();
    {
        const uint4v* src = (const uint4v*)stg;
        uint4v* dst = (uint4v*)((float*)out + (size_t)BB_ * TT + (size_t)rbase * TT);
        for (int idx = tid; idx < 1600; idx += 256)
            __builtin_nontemporal_store(src[idx], dst + idx);
    }
}

// ---------------------------------------------------------------- launch
extern "C" void kernel_launch(void* const* d_in, const int* in_sizes, int n_in,
                              void* d_out, int out_size, void* d_ws, size_t ws_size,
                              hipStream_t stream) {
    const int* X = (const int*)d_in[0];
    const int* y = (const int*)d_in[1];
    float* table = (float*)d_ws;               // 1000 x 8 f32 = 32 KB

    aux_kernel<<<dim3(250, 1, 1), 256, 0, stream>>>(
        d_in[2], d_in[3], d_in[4], d_in[5], d_in[6], d_in[7], d_in[8], table);
    scan_kernel<<<dim3(2048, 1, 1), 256, 0, stream>>>(
        X, y, table, (const uint*)d_in[2], (void*)d_out);
}

// Round 9
// 203.960 us; speedup vs baseline: 1.9577x; 1.9019x over previous
//
#include <hip/hip_runtime.h>

// MLP depends only on X[b] (1000 distinct values) -> params table, gathered
// by the scan. R9 = consolidation of proven-best parts:
//   aux chain = R6's prep + MFMA mlp_layer x2 + params (measured ~55us total;
//     R8's block-local VALU MLP was 220us — latency-serialized by per-load
//     runtime-dtype branches at 1 block/CU. R7's cooperative grid.sync cost
//     ~60us per barrier. Both rejected on counters.)
//   scan = R7/R8's fused two-pass checkpoint kernel (exact; LDS checkpoints;
//     LDS-staged contiguous stores — R5 showed strided lane stores cause
//     4.85x HBM write amplification).

typedef unsigned int uint;
typedef unsigned char uchar;
typedef unsigned short ushort_t;
typedef __attribute__((ext_vector_type(8))) short short8;
typedef __attribute__((ext_vector_type(4))) float f32x4;
typedef __attribute__((ext_vector_type(4))) uint uint4v;

#define SS 1000
#define HH 512
#define TT 200
#define BB_ 65536
#define PP 5

#define OFF_EMB   0
#define OFF_B1    512000
#define OFF_B2    512512
#define OFF_WOUT  513024
#define OFF_BOUT  515584
#define CONV_TOT  515589

__device__ __forceinline__ float b2f(ushort_t u) {
    return __uint_as_float(((uint)u) << 16);
}
__device__ __forceinline__ ushort_t f2b(float f) {
    uint u = __float_as_uint(f);
    uint r = u + 0x7FFFu + ((u >> 16) & 1u);   // RNE
    return (ushort_t)(r >> 16);
}
// Per-wave dtype detect (R2-R8: dataset is f32; keep both paths).
__device__ __forceinline__ int detect_bf16(const uint* __restrict__ embed_raw,
                                           int tid) {
    uint w = embed_raw[tid & 63];
    uint e = (w >> 7) & 0xFFu;
    bool pl = (e >= 117u && e <= 130u);
    return __popcll(__ballot(pl)) >= 32 ? 1 : 0;
}
__device__ __forceinline__ ushort_t ld_bf16(const void* src, int idx, int fb) {
    return fb ? ((const ushort_t*)src)[idx] : f2b(((const float*)src)[idx]);
}

// The one true scan step. Identical fp ops/order in phase A and phase B so
// checkpoint-resumed trajectories are bit-exact.
__device__ __forceinline__ float bkt_step(float latent, bool yt,
                                          float oms, float omg, float A1,
                                          float A0, float g, float s,
                                          float oml, float l,
                                          float* correct_out) {
    float num1    = latent * oms;
    float correct = fmaf(latent, A1, g);
    float lats    = latent * s;
    float num = yt ? num1 : lats;
    float den = yt ? correct : fmaf(latent, A0, omg);
    float kt  = num * __builtin_amdgcn_rcpf(den);
    *correct_out = correct;
    float nxt = fmaf(kt, oml, l);
    return fminf(fmaxf(nxt, 1e-6f), 1.f - 1e-6f);
}

// ------------------------------------------------------------------- prep
// [0,2015): conv copy (bf16 canonicalize). [2015,2527): 32x32 transpose
// tiles of W1/W2 (read raw, emit bf16 WT).
__global__ __launch_bounds__(256) void prep_kernel(
    const void* __restrict__ embed, const void* __restrict__ W1,
    const void* __restrict__ b1,    const void* __restrict__ W2,
    const void* __restrict__ b2,    const void* __restrict__ Wout,
    const void* __restrict__ bout,
    ushort_t* __restrict__ conv, ushort_t* __restrict__ WT1,
    ushort_t* __restrict__ WT2)
{
    int tid = threadIdx.x;
    int fb = detect_bf16((const uint*)embed, tid);
    int bx = blockIdx.x;
    if (bx < 2015) {
        int i = bx * 256 + tid;
        if (i < CONV_TOT) {
            const void* src; int off;
            if      (i < OFF_B1)   { src = embed; off = i; }
            else if (i < OFF_B2)   { src = b1;    off = i - OFF_B1; }
            else if (i < OFF_WOUT) { src = b2;    off = i - OFF_B2; }
            else if (i < OFF_BOUT) { src = Wout;  off = i - OFF_WOUT; }
            else                   { src = bout;  off = i - OFF_BOUT; }
            conv[i] = ld_bf16(src, off, fb);
        }
    } else {
        __shared__ ushort_t t[32][33];
        int bi = bx - 2015;
        const void* W = bi < 256 ? W1 : W2;
        ushort_t* WT = bi < 256 ? WT1 : WT2;
        int ti = bi & 255;
        int k0 = (ti & 15) * 32, n0 = (ti >> 4) * 32;
        int tx = tid & 31, ty = tid >> 5;
        #pragma unroll
        for (int i = ty; i < 32; i += 8)
            t[i][tx] = ld_bf16(W, (k0 + i) * HH + n0 + tx, fb);
        __syncthreads();
        #pragma unroll
        for (int i = ty; i < 32; i += 8)
            WT[(n0 + i) * HH + k0 + tx] = t[tx][i];
    }
}

// -------------------------------------------------------------- MLP layer
// Wave computes a 16x16 MFMA tile; grid (16,32)=512 blocks (2/CU).
__global__ __launch_bounds__(256) void mlp_layer(
    const ushort_t* __restrict__ A, const ushort_t* __restrict__ WT,
    const ushort_t* __restrict__ bias, ushort_t* __restrict__ H, int Mclamp)
{
    int tid = threadIdx.x;
    int lane = tid & 63;
    int wave = tid >> 6;
    int m_base = blockIdx.x * 64 + wave * 16;
    int n_base = blockIdx.y * 16;
    int lrow = lane & 15;
    int q = lane >> 4;
    int rowA = m_base + lrow; if (rowA > Mclamp) rowA = Mclamp;

    const short8* Ap = (const short8*)(A + (size_t)rowA * HH) + q;
    const short8* Bp = (const short8*)(WT + (size_t)(n_base + lrow) * HH) + q;

    f32x4 acc = {0.f, 0.f, 0.f, 0.f};
    #pragma unroll 8
    for (int kk = 0; kk < 16; kk++) {
        short8 a = Ap[kk * 4];
        short8 b = Bp[kk * 4];
        acc = __builtin_amdgcn_mfma_f32_16x16x32_bf16(a, b, acc, 0, 0, 0);
    }

    int orow = m_base + q * 4;                 // C/D: col=lane&15, row=q*4+reg
    int n = n_base + lrow;
    float bb = b2f(bias[n]);
    #pragma unroll
    for (int r = 0; r < 4; r++) {
        float v = acc[r] + bb;
        H[(size_t)(orow + r) * HH + n] = f2b(fmaxf(v, 0.f));
    }
}

// ---------------------------------------------------------------- params
__global__ __launch_bounds__(256) void params_kernel(
    const ushort_t* __restrict__ h2, const ushort_t* __restrict__ conv,
    float* __restrict__ table)
{
    int wid = blockIdx.x * 4 + (threadIdx.x >> 6);
    int lane = threadIdx.x & 63;
    if (wid >= SS * PP) return;
    int row = wid / PP, p = wid - row * PP;
    const ushort_t* Wout = conv + OFF_WOUT;
    const ushort_t* bout = conv + OFF_BOUT;
    const short8* hr = (const short8*)(h2 + (size_t)row * HH);
    short8 h = hr[lane];
    float acc = 0.f;
    #pragma unroll
    for (int j = 0; j < 8; j++) {
        int k = lane * 8 + j;
        acc += b2f((ushort_t)h[j]) * b2f(Wout[k * PP + p]);
    }
    #pragma unroll
    for (int m = 32; m; m >>= 1) acc += __shfl_xor(acc, m);
    if (lane == 0) {
        float x = acc + b2f(bout[p]);
        float sg = 1.f / (1.f + expf(-x));
        sg = fminf(fmaxf(sg, 1e-6f), 1.f - 1e-6f);
        table[(size_t)row * 8 + p] = sg;
    }
}

// ---------------------------------------------------------------- scan
// One block = 32 rows. Phase 0: y staged coalesced -> LDS nibbles.
// Phase A: 32 threads run the exact 200-step chain, drop 8 checkpoints+masks
// to LDS. Phase B: 256 threads (8/row) re-emit bit-identically into a
// 32x200 LDS tile; contiguous nontemporal uint4 stores.
__global__ __launch_bounds__(256) void scan_kernel(
    const int* __restrict__ X, const int* __restrict__ y,
    const float* __restrict__ table, const uint* __restrict__ embed_raw,
    void* __restrict__ out)
{
    __shared__ __align__(16) float stg[32 * 200];      // 25600 B
    __shared__ uchar ybit[32 * 50];                    // 1600 B
    __shared__ float cpL[8 * 32];
    __shared__ uint  maskL[8 * 32];
    int tid = threadIdx.x;
    int rbase = blockIdx.x * 32;
    int fb = detect_bf16(embed_raw, tid);

    for (int idx = tid; idx < 1600; idx += 256) {
        int r = idx / 50, k = idx - r * 50;
        int4 v = *(const int4*)(y + (size_t)(rbase + r) * TT + k * 4);
        uint nib = (uint)(v.x == 1) | ((uint)(v.y == 1) << 1) |
                   ((uint)(v.z == 1) << 2) | ((uint)(v.w == 1) << 3);
        ybit[r * 50 + k] = (uchar)nib;
    }
    __syncthreads();

    if (tid < 32) {
        int rg = rbase + tid;
        int xi = X[rg]; xi = xi < 0 ? 0 : (xi >= SS ? SS - 1 : xi);
        float l      = table[xi * 8 + 0];
        float g      = table[xi * 8 + 2];
        float s      = table[xi * 8 + 3];
        float latent = table[xi * 8 + 4];
        float oms = 1.f - s, omg = 1.f - g, oml = 1.f - l;
        float A1 = 1.f - s - g, A0 = s + g - 1.f;
        int base = tid * 50;
        #pragma unroll
        for (int w = 0; w < 8; w++) {
            cpL[w * 32 + tid] = latent;
            uint m = 0;
            #pragma unroll
            for (int i = 0; i < 25; i++) {
                int t_ = w * 25 + i;
                uint bit = (ybit[base + (t_ >> 2)] >> (t_ & 3)) & 1u;
                m |= bit << i;
                float cd;
                latent = bkt_step(latent, bit, oms, omg, A1, A0, g, s, oml, l, &cd);
            }
            maskL[w * 32 + tid] = m;
        }
    }
    __syncthreads();

    int r = tid >> 3, j = tid & 7;
    int rg = rbase + r;
    int xi = X[rg]; xi = xi < 0 ? 0 : (xi >= SS ? SS - 1 : xi);
    float l  = table[xi * 8 + 0];
    float p1 = table[xi * 8 + 1];
    float g  = table[xi * 8 + 2];
    float s  = table[xi * 8 + 3];
    float L0 = table[xi * 8 + 4];

    if (j < 5) {
        float pv = j == 0 ? l : j == 1 ? p1 : j == 2 ? g : j == 3 ? s : L0;
        size_t po = 2ull * BB_ * TT + (size_t)rg * 5 + j;
        if (fb) ((ushort_t*)out)[po] = f2b(pv);
        else    ((float*)out)[po] = pv;
    }

    float latent = cpL[j * 32 + r];
    uint  u      = maskL[j * 32 + r];
    float oms = 1.f - s, omg = 1.f - g, oml = 1.f - l;
    float A1 = 1.f - s - g, A0 = s + g - 1.f;

    if (fb) {
        ushort_t* cgb = (ushort_t*)out;
        ushort_t* lgb = (ushort_t*)out + (size_t)BB_ * TT;
        size_t eoff = (size_t)rg * TT + j * 25;
        #pragma unroll
        for (int i = 0; i < 25; i++) {
            float correct;
            float nxt = bkt_step(latent, (u >> i) & 1u,
                                 oms, omg, A1, A0, g, s, oml, l, &correct);
            cgb[eoff + i] = f2b(correct);
            lgb[eoff + i] = f2b(latent);
            latent = nxt;
        }
        return;                                // grid-uniform branch
    }

    float lat_arr[25];
    int sbase = r * 200 + j * 25;              // 2-way bank alias = free
    #pragma unroll
    for (int i = 0; i < 25; i++) {
        float correct;
        float nxt = bkt_step(latent, (u >> i) & 1u,
                             oms, omg, A1, A0, g, s, oml, l, &correct);
        stg[sbase + i] = correct;
        lat_arr[i] = latent;
        latent = nxt;
    }
    __syncthreads();
    {
        const uint4v* src = (const uint4v*)stg;
        uint4v* dst = (uint4v*)((float*)out + (size_t)rbase * TT);
        for (int idx = tid; idx < 1600; idx += 256)
            __builtin_nontemporal_store(src[idx], dst + idx);
    }
    __syncthreads();
    #pragma unroll
    for (int i = 0; i < 25; i++)
        stg[sbase + i] = lat_arr[i];
    __syncthreads();
    {
        const uint4v* src = (const uint4v*)stg;
        uint4v* dst = (uint4v*)((float*)out + (size_t)BB_ * TT + (size_t)rbase * TT);
        for (int idx = tid; idx < 1600; idx += 256)
            __builtin_nontemporal_store(src[idx], dst + idx);
    }
}

// ---------------------------------------------------------------- launch
extern "C" void kernel_launch(void* const* d_in, const int* in_sizes, int n_in,
                              void* d_out, int out_size, void* d_ws, size_t ws_size,
                              hipStream_t stream) {
    const int* X = (const int*)d_in[0];
    const int* y = (const int*)d_in[1];

    char* ws = (char*)d_ws;
    ushort_t* conv  = (ushort_t*)(ws);                 // ~1.03 MB used
    ushort_t* WT1   = (ushort_t*)(ws + 1048576);       // 512 KB
    ushort_t* WT2   = (ushort_t*)(ws + 1572864);       // 512 KB
    ushort_t* h1    = (ushort_t*)(ws + 2097152);       // 1 MB
    ushort_t* h2    = (ushort_t*)(ws + 3145728);       // 1 MB
    float*    table = (float*)(ws + 4194304);          // 32 KB

    prep_kernel<<<dim3(2527, 1, 1), 256, 0, stream>>>(
        d_in[2], d_in[3], d_in[4], d_in[5], d_in[6], d_in[7], d_in[8],
        conv, WT1, WT2);
    mlp_layer<<<dim3(16, 32, 1), 256, 0, stream>>>(conv + OFF_EMB, WT1, conv + OFF_B1, h1, SS - 1);
    mlp_layer<<<dim3(16, 32, 1), 256, 0, stream>>>(h1, WT2, conv + OFF_B2, h2, 1023);
    params_kernel<<<dim3(1250, 1, 1), 256, 0, stream>>>(h2, conv, table);
    scan_kernel<<<dim3(2048, 1, 1), 256, 0, stream>>>(
        X, y, table, (const uint*)d_in[2], (void*)d_out);
}